// Round 5
// baseline (278.995 us; speedup 1.0000x reference)
//
#include <hip/hip_runtime.h>
#include <cstdint>

typedef unsigned short u16;
typedef __bf16 bf16x8 __attribute__((ext_vector_type(8)));
typedef float f32x4 __attribute__((ext_vector_type(4)));

#define T_SEQ  2048
#define D_DIM  1024
#define H_DIM  512
#define E_NUM  8
#define M_TOK  2048
#define BT_TOK 4096
#define MAXP   3072   // M + per-expert 128-pad worst case (2048 + 7*127 -> <=3072)

static __device__ __forceinline__ u16 f2bf(float f) {
    union { float f; uint32_t u; } v; v.f = f;
    uint32_t u = v.u;
    return (u16)((u + 0x7FFFu + ((u >> 16) & 1u)) >> 16);  // RNE (epilogue/LN)
}
// round-half-up bf16 pack of two floats (compiles to 2 adds + v_perm)
static __device__ __forceinline__ uint32_t pack2r(float a, float b) {
    union { float f; uint32_t u; } x, y; x.f = a; y.f = b;
    return ((x.u + 0x8000u) >> 16) | ((y.u + 0x8000u) & 0xffff0000u);
}

// ---------------- gating: fp32 dots, sigmoid, argmax, 2-way softmax ----------------
__global__ __launch_bounds__(256)
void gating_kernel(const float* __restrict__ x,
                   const int* __restrict__ ib, const int* __restrict__ itx,
                   const float* __restrict__ sgw, const float* __restrict__ sgb,
                   const float* __restrict__ egw, const float* __restrict__ egb,
                   const float* __restrict__ ebias,
                   float* __restrict__ shw, float* __restrict__ expw,
                   int* __restrict__ top1, int* __restrict__ rowidx)
{
    int m = blockIdx.x, tid = threadIdx.x;
    __shared__ float xs[D_DIM];
    __shared__ float sc[9];
    int row = ib[m] * T_SEQ + itx[m];
    if (tid == 0) rowidx[m] = row;
    const float* xr = x + (size_t)row * D_DIM;
    ((float4*)xs)[tid] = ((const float4*)xr)[tid];
    __syncthreads();
    int lane = tid & 63, w = tid >> 6;
    for (int sidx = w; sidx < 9; sidx += 4) {
        const float* wr = (sidx == 0) ? sgw : (egw + (size_t)(sidx - 1) * D_DIM);
        float acc = 0.f;
        for (int i = lane; i < D_DIM; i += 64) acc += xs[i] * wr[i];
        #pragma unroll
        for (int o = 32; o > 0; o >>= 1) acc += __shfl_xor(acc, o);
        if (lane == 0) sc[sidx] = acc;
    }
    __syncthreads();
    if (tid == 0) {
        float ss = 1.f / (1.f + expf(-(sc[0] + sgb[0])));
        float es[E_NUM];
        float best = -1e30f; int bi = 0;
        #pragma unroll
        for (int e = 0; e < E_NUM; ++e) {
            es[e] = 1.f / (1.f + expf(-(sc[1 + e] + egb[e])));
            float t = es[e] + ebias[e];
            if (t > best) { best = t; bi = e; }   // strict > == jnp.argmax first-max
        }
        float ts = es[bi];
        shw[m]  = 1.f / (1.f + expf(ts - ss));
        expw[m] = 1.f / (1.f + expf(ss - ts));
        top1[m] = bi;
    }
}

// ---------------- bucket tokens by expert, 128-aligned bases ----------------
__global__ void bucket_kernel(const int* __restrict__ top1,
                              int* __restrict__ base, int* __restrict__ cnt,
                              int* __restrict__ perm)
{
    __shared__ int lc[E_NUM], lb[E_NUM + 1], cur[E_NUM];
    int tid = threadIdx.x;
    if (tid < E_NUM) { lc[tid] = 0; cur[tid] = 0; }
    __syncthreads();
    for (int m = tid; m < M_TOK; m += 256) atomicAdd(&lc[top1[m]], 1);
    __syncthreads();
    if (tid == 0) {
        int bacc = 0;
        for (int e = 0; e < E_NUM; ++e) { lb[e] = bacc; bacc += (lc[e] + 127) & ~127; }
        lb[E_NUM] = bacc;
    }
    __syncthreads();
    for (int m = tid; m < M_TOK; m += 256) {
        int e = top1[m];
        int pos = lb[e] + atomicAdd(&cur[e], 1);
        perm[pos] = m;
    }
    if (tid <= E_NUM) base[tid] = lb[tid];
    if (tid < E_NUM)  cnt[tid]  = lc[tid];
}

// ---------------- silu-gate + LayerNorm, fp32 in -> bf16 out ----------------
template<bool SEL>
__global__ __launch_bounds__(256)
void ln_kernel(const float* __restrict__ X,
               const float* __restrict__ g, const float* __restrict__ b,
               u16* __restrict__ out,
               const int* __restrict__ base, const int* __restrict__ cnt)
{
    int m = blockIdx.x;
    int tid = threadIdx.x;
    if (SEL) {
        bool valid = false;
        int tot = base[E_NUM];
        if (m < tot) {
            int e = 0;
            while (!(m >= base[e] && m < base[e + 1])) ++e;
            valid = (m - base[e]) < cnt[e];
        }
        if (!valid) {  // zero padding rows so E2's A-tiles are clean
            out[(size_t)m * H_DIM + tid] = 0;
            out[(size_t)m * H_DIM + tid + 256] = 0;
            return;
        }
    }
    const float* row = X + (size_t)m * D_DIM;   // [0:512]=x1, [512:1024]=x2
    float a0 = row[tid],       c0 = row[H_DIM + tid];
    float a1 = row[tid + 256], c1 = row[H_DIM + tid + 256];
    float v0 = (a0 / (1.f + expf(-a0))) * c0;
    float v1 = (a1 / (1.f + expf(-a1))) * c1;
    float s = v0 + v1, s2 = v0 * v0 + v1 * v1;
    #pragma unroll
    for (int o = 32; o > 0; o >>= 1) {
        s  += __shfl_xor(s, o);
        s2 += __shfl_xor(s2, o);
    }
    __shared__ float red[8];
    int w = tid >> 6;
    if ((tid & 63) == 0) { red[w] = s; red[4 + w] = s2; }
    __syncthreads();
    s  = red[0] + red[1] + red[2] + red[3];
    s2 = red[4] + red[5] + red[6] + red[7];
    float mu  = s * (1.f / H_DIM);
    float var = s2 * (1.f / H_DIM) - mu * mu;
    float inv = rsqrtf(var + 1e-5f);
    out[(size_t)m * H_DIM + tid]       = f2bf((v0 - mu) * inv * g[tid] + b[tid]);
    out[(size_t)m * H_DIM + tid + 256] = f2bf((v1 - mu) * inv * g[tid + 256] + b[tid + 256]);
}

// ---------------- MFMA GEMM: 128x128 tile, 512 threads, BK=64 ----------------
// C[m][n] = sum_k A[m][k] * W[n][k] (+ epilogue). W always fp32 (in-register cvt).
// A fp32 (G1/E1: x) or bf16 (G2/E2: LN outputs). Register prefetch depth 1.
// MODE 0: G1  A=x fp32,          W=sw1|sw2 split 512 -> x12 fp32 (+sb1|sb2)
// MODE 1: G2  A=sh bf16,         W=sw3               -> d_out (+sb3)
// MODE 2: E1  A=x fp32 gathered, W=ew1|ew2[e]        -> h12 fp32 (+eb1|eb2[e])
// MODE 3: E2  A=z bf16 buckets,  W=ew3[e]            -> blend d_out[row]
template<int MODE, int KLEN, bool A_BF16>
__global__ __launch_bounds__(512, 2)
void gemm_kernel(const void* __restrict__ Av, int lda,
                 const float* __restrict__ W0, const float* __restrict__ W1, int nsplit,
                 const float* __restrict__ b0, const float* __restrict__ b1,
                 float* __restrict__ C,
                 const int* __restrict__ base, const int* __restrict__ cnt,
                 const int* __restrict__ perm, const int* __restrict__ rowidx,
                 const float* __restrict__ shw, const float* __restrict__ expw)
{
    constexpr int NITER = KLEN / 64;

    const int tid   = threadIdx.x;
    const int bn    = blockIdx.x;
    const int bm    = blockIdx.y;
    const int mbase = bm * 128;

    int pend = 0;
    if (MODE >= 2) {
        const int tot = base[E_NUM];
        if (mbase >= tot) return;          // block-uniform exits before any barrier
        int e = 0;
        while (!(mbase >= base[e] && mbase < base[e + 1])) ++e;
        pend = base[e] + cnt[e];
        if (mbase >= pend) return;         // all-pad tile: output never read
        const size_t wstride = (size_t)H_DIM * D_DIM;
        W0 += (size_t)e * wstride;
        if (MODE == 2) W1 += (size_t)e * wstride;
        b0 += e * ((MODE == 2) ? H_DIM : D_DIM);
        if (MODE == 2) b1 += e * H_DIM;
    }

    __shared__ u16 As[128 * 72];   // stride 72: <=2-way bank aliasing (free)
    __shared__ u16 Bs[128 * 72];

    const int srow = tid >> 2;     // 0..127: tile row staged by this thread
    const int skq  = tid & 3;      // 16-elem k-chunk within BK=64

    // K-invariant global row pointers
    const float* af = nullptr; const u16* ab = nullptr;
    if (MODE == 2) {
        int p  = mbase + srow;
        int pp = (p < pend) ? p : (pend - 1);   // clamp pad rows to a valid token
        int grow = rowidx[perm[pp]];
        af = (const float*)Av + (size_t)grow * lda + skq * 16;
    } else if (A_BF16) {
        ab = (const u16*)Av + (size_t)(mbase + srow) * lda + skq * 16;
    } else {
        af = (const float*)Av + (size_t)(mbase + srow) * lda + skq * 16;
    }
    int n = bn * 128 + srow;
    const float* wf = ((n < nsplit) ? (W0 + (size_t)n * KLEN)
                                    : (W1 + (size_t)(n - nsplit) * KLEN)) + skq * 16;

    const int lane = tid & 63;
    const int wid  = tid >> 6;         // 0..7
    const int wm   = wid & 3;          // 32-row band
    const int wn   = wid >> 2;         // 64-col band
    const int l16  = lane & 15, quad = lane >> 4;

    f32x4 acc[2][4];
    #pragma unroll
    for (int i = 0; i < 2; ++i)
        #pragma unroll
        for (int j = 0; j < 4; ++j)
            acc[i][j] = (f32x4){0.f, 0.f, 0.f, 0.f};

    const int kstart = (bm * 5 + bn * 3) & (NITER - 1);   // channel-spread rotation

    // prologue: prefetch K-tile 0
    float4 paf[4]; uint4 pau[2]; float4 pbf[4];
    {
        int k0 = kstart * 64;
        #pragma unroll
        for (int q = 0; q < 4; ++q) pbf[q] = *(const float4*)(wf + k0 + q * 4);
        if (A_BF16) {
            #pragma unroll
            for (int q = 0; q < 2; ++q) pau[q] = *(const uint4*)(ab + k0 + q * 8);
        } else {
            #pragma unroll
            for (int q = 0; q < 4; ++q) paf[q] = *(const float4*)(af + k0 + q * 4);
        }
    }

    for (int it = 0; it < NITER; ++it) {
        // convert + LDS store (waits on prefetched loads)
        uint4 sa0, sa1, sb0, sb1;
        if (A_BF16) { sa0 = pau[0]; sa1 = pau[1]; }
        else {
            sa0.x = pack2r(paf[0].x, paf[0].y); sa0.y = pack2r(paf[0].z, paf[0].w);
            sa0.z = pack2r(paf[1].x, paf[1].y); sa0.w = pack2r(paf[1].z, paf[1].w);
            sa1.x = pack2r(paf[2].x, paf[2].y); sa1.y = pack2r(paf[2].z, paf[2].w);
            sa1.z = pack2r(paf[3].x, paf[3].y); sa1.w = pack2r(paf[3].z, paf[3].w);
        }
        sb0.x = pack2r(pbf[0].x, pbf[0].y); sb0.y = pack2r(pbf[0].z, pbf[0].w);
        sb0.z = pack2r(pbf[1].x, pbf[1].y); sb0.w = pack2r(pbf[1].z, pbf[1].w);
        sb1.x = pack2r(pbf[2].x, pbf[2].y); sb1.y = pack2r(pbf[2].z, pbf[2].w);
        sb1.z = pack2r(pbf[3].x, pbf[3].y); sb1.w = pack2r(pbf[3].z, pbf[3].w);
        *(uint4*)(As + srow * 72 + skq * 16)     = sa0;
        *(uint4*)(As + srow * 72 + skq * 16 + 8) = sa1;
        *(uint4*)(Bs + srow * 72 + skq * 16)     = sb0;
        *(uint4*)(Bs + srow * 72 + skq * 16 + 8) = sb1;
        __syncthreads();
        if (it + 1 < NITER) {   // prefetch next K-tile: in flight across MFMA + barrier
            int k0 = (((it + 1 + kstart) & (NITER - 1))) * 64;
            #pragma unroll
            for (int q = 0; q < 4; ++q) pbf[q] = *(const float4*)(wf + k0 + q * 4);
            if (A_BF16) {
                #pragma unroll
                for (int q = 0; q < 2; ++q) pau[q] = *(const uint4*)(ab + k0 + q * 8);
            } else {
                #pragma unroll
                for (int q = 0; q < 4; ++q) paf[q] = *(const float4*)(af + k0 + q * 4);
            }
        }
        #pragma unroll
        for (int kk = 0; kk < 64; kk += 32) {
            bf16x8 av[2], bv[4];
            #pragma unroll
            for (int i = 0; i < 2; ++i)
                av[i] = *(const bf16x8*)(As + (wm * 32 + i * 16 + l16) * 72 + kk + quad * 8);
            #pragma unroll
            for (int j = 0; j < 4; ++j)
                bv[j] = *(const bf16x8*)(Bs + (wn * 64 + j * 16 + l16) * 72 + kk + quad * 8);
            #pragma unroll
            for (int i = 0; i < 2; ++i)
                #pragma unroll
                for (int j = 0; j < 4; ++j)
                    acc[i][j] = __builtin_amdgcn_mfma_f32_16x16x32_bf16(av[i], bv[j], acc[i][j], 0, 0, 0);
        }
        __syncthreads();
    }

    if (MODE == 3) {
        #pragma unroll
        for (int i = 0; i < 2; ++i) {
            #pragma unroll
            for (int rr = 0; rr < 4; ++rr) {
                int p = mbase + wm * 32 + i * 16 + quad * 4 + rr;
                if (p < pend) {
                    int tok = perm[p];
                    int row = rowidx[tok];
                    float sw = shw[tok], ew = expw[tok];
                    float* outr = C + (size_t)row * D_DIM;
                    #pragma unroll
                    for (int j = 0; j < 4; ++j) {
                        int gn = bn * 128 + wn * 64 + j * 16 + l16;
                        outr[gn] = outr[gn] * sw + (acc[i][j][rr] + b0[gn]) * ew;
                    }
                }
            }
        }
    } else {
        #pragma unroll
        for (int i = 0; i < 2; ++i) {
            #pragma unroll
            for (int rr = 0; rr < 4; ++rr) {
                int gm = mbase + wm * 32 + i * 16 + quad * 4 + rr;
                float* outr = C + (size_t)gm * D_DIM;
                #pragma unroll
                for (int j = 0; j < 4; ++j) {
                    int gn = bn * 128 + wn * 64 + j * 16 + l16;
                    float bias = (gn < nsplit) ? b0[gn] : b1[gn - nsplit];
                    outr[gn] = acc[i][j][rr] + bias;
                }
            }
        }
    }
}

extern "C" void kernel_launch(void* const* d_in, const int* in_sizes, int n_in,
                              void* d_out, int out_size, void* d_ws, size_t ws_size,
                              hipStream_t stream) {
    const float* x        = (const float*)d_in[0];
    const int*   index_b  = (const int*)d_in[1];
    const int*   index_t  = (const int*)d_in[2];
    const float* sw1      = (const float*)d_in[3];
    const float* sb1      = (const float*)d_in[4];
    const float* sw2      = (const float*)d_in[5];
    const float* sb2      = (const float*)d_in[6];
    const float* sw3      = (const float*)d_in[7];
    const float* sb3      = (const float*)d_in[8];
    const float* s_ln_g   = (const float*)d_in[9];
    const float* s_ln_b   = (const float*)d_in[10];
    const float* sg_w     = (const float*)d_in[11];
    const float* sg_b     = (const float*)d_in[12];
    const float* eg_w     = (const float*)d_in[13];
    const float* eg_b     = (const float*)d_in[14];
    const float* exp_bias = (const float*)d_in[15];
    const float* ew1      = (const float*)d_in[16];
    const float* eb1      = (const float*)d_in[17];
    const float* ew2      = (const float*)d_in[18];
    const float* eb2      = (const float*)d_in[19];
    const float* ew3      = (const float*)d_in[20];
    const float* eb3      = (const float*)d_in[21];
    const float* sel_ln_g = (const float*)d_in[22];
    const float* sel_ln_b = (const float*)d_in[23];
    float* out = (float*)d_out;
    char*  ws  = (char*)d_ws;

    // ---- ws layout ----
    // x12: [0, 16777216)          4096x1024 fp32 (h12 aliases: 3072x1024 fp32)
    // sh : [16777216, 20971520)   4096x512 bf16 (z aliases: 3072x512)
    // misc thereafter
    float* x12  = (float*)(ws + 0);
    float* h12  = x12;
    u16*   sh   = (u16*)(ws + 16777216);
    u16*   z    = sh;
    float* shw    = (float*)(ws + 20971520);
    float* expw   = shw + M_TOK;
    int*   top1   = (int*)(expw + M_TOK);
    int*   rowidx = top1 + M_TOK;
    int*   perm   = rowidx + M_TOK;
    int*   basep  = perm + MAXP;
    int*   cntp   = basep + 16;

    const int NSPLIT_NONE = 1 << 28;

    gating_kernel<<<dim3(M_TOK), dim3(256), 0, stream>>>(x, index_b, index_t,
        sg_w, sg_b, eg_w, eg_b, exp_bias, shw, expw, top1, rowidx);
    bucket_kernel<<<dim3(1), dim3(256), 0, stream>>>(top1, basep, cntp, perm);

    // G1: x @ [sw1;sw2]^T -> x12. 256 blocks.
    gemm_kernel<0, 1024, false><<<dim3(8, 32), dim3(512), 0, stream>>>(
        x, D_DIM, sw1, sw2, H_DIM, sb1, sb2, x12,
        basep, cntp, perm, rowidx, shw, expw);
    // shared silu-gate + LN -> sh
    ln_kernel<false><<<dim3(BT_TOK), dim3(256), 0, stream>>>(
        x12, s_ln_g, s_ln_b, sh, basep, cntp);
    // G2: sh @ sw3^T -> d_out (all rows). 256 blocks.
    gemm_kernel<1, 512, true><<<dim3(8, 32), dim3(512), 0, stream>>>(
        sh, H_DIM, sw3, sw3, NSPLIT_NONE, sb3, sb3, out,
        basep, cntp, perm, rowidx, shw, expw);
    // E1: gathered x @ [ew1;ew2][e]^T -> h12. <=192 blocks.
    gemm_kernel<2, 1024, false><<<dim3(8, MAXP / 128), dim3(512), 0, stream>>>(
        x, D_DIM, ew1, ew2, H_DIM, eb1, eb2, h12,
        basep, cntp, perm, rowidx, shw, expw);
    // expert silu-gate + LN -> z (pad rows zeroed)
    ln_kernel<true><<<dim3(MAXP), dim3(256), 0, stream>>>(
        h12, sel_ln_g, sel_ln_b, z, basep, cntp);
    // E2: z @ ew3[e]^T, blend-scatter into d_out. <=192 blocks.
    gemm_kernel<3, 512, true><<<dim3(8, MAXP / 128), dim3(512), 0, stream>>>(
        z, H_DIM, ew3, ew3, NSPLIT_NONE, eb3, eb3, out,
        basep, cntp, perm, rowidx, shw, expw);
}

// Round 6
// 266.487 us; speedup vs baseline: 1.0469x; 1.0469x over previous
//
#include <hip/hip_runtime.h>
#include <cstdint>

typedef unsigned short u16;
typedef __bf16 bf16x8 __attribute__((ext_vector_type(8)));
typedef float f32x4 __attribute__((ext_vector_type(4)));

#define T_SEQ  2048
#define D_DIM  1024
#define H_DIM  512
#define E_NUM  8
#define M_TOK  2048
#define BT_TOK 4096
#define MAXP   3072   // M + per-expert 128-pad worst case

static __device__ __forceinline__ u16 f2bf(float f) {
    union { float f; uint32_t u; } v; v.f = f;
    uint32_t u = v.u;
    return (u16)((u + 0x7FFFu + ((u >> 16) & 1u)) >> 16);  // RNE
}
// round-half-up bf16 pack of two floats (2 adds + v_perm)
static __device__ __forceinline__ uint32_t pack2r(float a, float b) {
    union { float f; uint32_t u; } x, y; x.f = a; y.f = b;
    return ((x.u + 0x8000u) >> 16) | ((y.u + 0x8000u) & 0xffff0000u);
}

// ---------------- gating: fp32 dots, sigmoid, argmax, 2-way softmax ----------------
__global__ __launch_bounds__(256)
void gating_kernel(const float* __restrict__ x,
                   const int* __restrict__ ib, const int* __restrict__ itx,
                   const float* __restrict__ sgw, const float* __restrict__ sgb,
                   const float* __restrict__ egw, const float* __restrict__ egb,
                   const float* __restrict__ ebias,
                   float* __restrict__ shw, float* __restrict__ expw,
                   int* __restrict__ top1, int* __restrict__ rowidx)
{
    int m = blockIdx.x, tid = threadIdx.x;
    __shared__ float xs[D_DIM];
    __shared__ float sc[9];
    int row = ib[m] * T_SEQ + itx[m];
    if (tid == 0) rowidx[m] = row;
    const float* xr = x + (size_t)row * D_DIM;
    ((float4*)xs)[tid] = ((const float4*)xr)[tid];
    __syncthreads();
    int lane = tid & 63, w = tid >> 6;
    for (int sidx = w; sidx < 9; sidx += 4) {
        const float* wr = (sidx == 0) ? sgw : (egw + (size_t)(sidx - 1) * D_DIM);
        float acc = 0.f;
        for (int i = lane; i < D_DIM; i += 64) acc += xs[i] * wr[i];
        #pragma unroll
        for (int o = 32; o > 0; o >>= 1) acc += __shfl_xor(acc, o);
        if (lane == 0) sc[sidx] = acc;
    }
    __syncthreads();
    if (tid == 0) {
        float ss = 1.f / (1.f + expf(-(sc[0] + sgb[0])));
        float es[E_NUM];
        float best = -1e30f; int bi = 0;
        #pragma unroll
        for (int e = 0; e < E_NUM; ++e) {
            es[e] = 1.f / (1.f + expf(-(sc[1 + e] + egb[e])));
            float t = es[e] + ebias[e];
            if (t > best) { best = t; bi = e; }   // strict > == jnp.argmax first-max
        }
        float ts = es[bi];
        shw[m]  = 1.f / (1.f + expf(ts - ss));
        expw[m] = 1.f / (1.f + expf(ss - ts));
        top1[m] = bi;
    }
}

// ---------------- bucket tokens by expert, 128-aligned bases ----------------
__global__ void bucket_kernel(const int* __restrict__ top1,
                              int* __restrict__ base, int* __restrict__ cnt,
                              int* __restrict__ perm)
{
    __shared__ int lc[E_NUM], lb[E_NUM + 1], cur[E_NUM];
    int tid = threadIdx.x;
    if (tid < E_NUM) { lc[tid] = 0; cur[tid] = 0; }
    __syncthreads();
    for (int m = tid; m < M_TOK; m += 256) atomicAdd(&lc[top1[m]], 1);
    __syncthreads();
    if (tid == 0) {
        int bacc = 0;
        for (int e = 0; e < E_NUM; ++e) { lb[e] = bacc; bacc += (lc[e] + 127) & ~127; }
        lb[E_NUM] = bacc;
    }
    __syncthreads();
    for (int m = tid; m < M_TOK; m += 256) {
        int e = top1[m];
        int pos = lb[e] + atomicAdd(&cur[e], 1);
        perm[pos] = m;
    }
    if (tid <= E_NUM) base[tid] = lb[tid];
    if (tid < E_NUM)  cnt[tid]  = lc[tid];
}

// ---------------- fused silu-gate + LayerNorm (shared rows + expert rows) ----------------
__global__ __launch_bounds__(256)
void ln_all_kernel(const float* __restrict__ x12, const float* __restrict__ h12,
                   const float* __restrict__ gs, const float* __restrict__ bs,
                   const float* __restrict__ ge, const float* __restrict__ be,
                   u16* __restrict__ sh, u16* __restrict__ z,
                   const int* __restrict__ base, const int* __restrict__ cnt)
{
    int m = blockIdx.x;
    int tid = threadIdx.x;
    const float* X; const float* g; const float* b; u16* out; int row;
    if (m < BT_TOK) {
        X = x12; g = gs; b = bs; out = sh; row = m;
    } else {
        row = m - BT_TOK;
        int tot = base[E_NUM];
        bool valid = false;
        if (row < tot) {
            int e = 0;
            while (!(row >= base[e] && row < base[e + 1])) ++e;
            valid = (row - base[e]) < cnt[e];
        }
        if (!valid) {  // zero padding rows so E2's A-tiles are clean
            z[(size_t)row * H_DIM + tid] = 0;
            z[(size_t)row * H_DIM + tid + 256] = 0;
            return;
        }
        X = h12; g = ge; b = be; out = z;
    }
    const float* rp = X + (size_t)row * D_DIM;   // [0:512]=x1, [512:1024]=x2
    float a0 = rp[tid],       c0 = rp[H_DIM + tid];
    float a1 = rp[tid + 256], c1 = rp[H_DIM + tid + 256];
    float v0 = (a0 / (1.f + expf(-a0))) * c0;
    float v1 = (a1 / (1.f + expf(-a1))) * c1;
    float s = v0 + v1, s2 = v0 * v0 + v1 * v1;
    #pragma unroll
    for (int o = 32; o > 0; o >>= 1) {
        s  += __shfl_xor(s, o);
        s2 += __shfl_xor(s2, o);
    }
    __shared__ float red[8];
    int w = tid >> 6;
    if ((tid & 63) == 0) { red[w] = s; red[4 + w] = s2; }
    __syncthreads();
    s  = red[0] + red[1] + red[2] + red[3];
    s2 = red[4] + red[5] + red[6] + red[7];
    float mu  = s * (1.f / H_DIM);
    float var = s2 * (1.f / H_DIM) - mu * mu;
    float inv = rsqrtf(var + 1e-5f);
    out[(size_t)row * H_DIM + tid]       = f2bf((v0 - mu) * inv * g[tid] + b[tid]);
    out[(size_t)row * H_DIM + tid + 256] = f2bf((v1 - mu) * inv * g[tid + 256] + b[tid + 256]);
}

// ---------------- fused up-GEMM (G1 + E1): 128x128 tile, 512 thr, K=1024 ----------------
// bm < 32  : G1  rows m=bm*128.., A=x dense,    W=sw1|sw2, out=x12 (+sb1|sb2)
// bm >= 32 : E1  bucket tile,     A=x gathered, W=ew1|ew2[e], out=h12 (+eb1|eb2[e])
// Staging: fp32, 16 lanes cover one row's contiguous 256B k-slice (full coalescing).
__global__ __launch_bounds__(512, 4)
void gemm_up_kernel(const float* __restrict__ x,
                    const float* __restrict__ sw1, const float* __restrict__ sw2,
                    const float* __restrict__ sb1, const float* __restrict__ sb2,
                    const float* __restrict__ ew1, const float* __restrict__ ew2,
                    const float* __restrict__ eb1, const float* __restrict__ eb2,
                    float* __restrict__ x12, float* __restrict__ h12,
                    const int* __restrict__ base, const int* __restrict__ cnt,
                    const int* __restrict__ perm, const int* __restrict__ rowidx)
{
    constexpr int NITER = 1024 / 64;
    const int tid = threadIdx.x;
    const int bn  = blockIdx.x;            // 0..7
    const int bm  = blockIdx.y;            // 0..55

    const int sr = tid >> 4;               // 0..31 row-in-round
    const int sc = tid & 15;               // 16B chunk (float4) within 256B k-slice

    const float *W0, *W1, *B0, *B1;
    float* Cout;
    int mbase;
    const float* arow[4];                  // K-invariant A row pointers (4 rounds)

    if (bm < 32) {                         // ---- G1 ----
        mbase = bm * 128;
        W0 = sw1; W1 = sw2; B0 = sb1; B1 = sb2;
        Cout = x12;
        #pragma unroll
        for (int t = 0; t < 4; ++t)
            arow[t] = x + (size_t)(mbase + t * 32 + sr) * D_DIM + sc * 4;
    } else {                               // ---- E1 ----
        mbase = (bm - 32) * 128;
        const int tot = base[E_NUM];
        if (mbase >= tot) return;          // block-uniform exit before any barrier
        int e = 0;
        while (!(mbase >= base[e] && mbase < base[e + 1])) ++e;
        const int pend = base[e] + cnt[e];
        if (mbase >= pend) return;
        W0 = ew1 + (size_t)e * H_DIM * D_DIM;
        W1 = ew2 + (size_t)e * H_DIM * D_DIM;
        B0 = eb1 + e * H_DIM;
        B1 = eb2 + e * H_DIM;
        Cout = h12;
        #pragma unroll
        for (int t = 0; t < 4; ++t) {
            int p  = mbase + t * 32 + sr;
            int pp = (p < pend) ? p : (pend - 1);   // clamp pad rows
            arow[t] = x + (size_t)rowidx[perm[pp]] * D_DIM + sc * 4;
        }
    }
    const float* wrow[4];
    #pragma unroll
    for (int t = 0; t < 4; ++t) {
        int n = bn * 128 + t * 32 + sr;
        wrow[t] = ((n < H_DIM) ? (W0 + (size_t)n * D_DIM)
                               : (W1 + (size_t)(n - H_DIM) * D_DIM)) + sc * 4;
    }

    __shared__ u16 As[128 * 72];
    __shared__ u16 Bs[128 * 72];

    const int lane = tid & 63;
    const int wid  = tid >> 6;             // 0..7
    const int wm   = wid & 3;              // 32-row band
    const int wn   = wid >> 2;             // 64-col band
    const int l16  = lane & 15, quad = lane >> 4;

    f32x4 acc[2][4];
    #pragma unroll
    for (int i = 0; i < 2; ++i)
        #pragma unroll
        for (int j = 0; j < 4; ++j)
            acc[i][j] = (f32x4){0.f, 0.f, 0.f, 0.f};

    float4 pa[4], pb[4];
    #pragma unroll
    for (int t = 0; t < 4; ++t) { pa[t] = *(const float4*)(arow[t]); pb[t] = *(const float4*)(wrow[t]); }

    for (int it = 0; it < NITER; ++it) {
        #pragma unroll
        for (int t = 0; t < 4; ++t) {      // cvt + coalesced 8B LDS stores
            int r = t * 32 + sr;
            uint2 av = { pack2r(pa[t].x, pa[t].y), pack2r(pa[t].z, pa[t].w) };
            uint2 bv = { pack2r(pb[t].x, pb[t].y), pack2r(pb[t].z, pb[t].w) };
            *(uint2*)(As + r * 72 + sc * 4) = av;
            *(uint2*)(Bs + r * 72 + sc * 4) = bv;
        }
        __syncthreads();
        if (it + 1 < NITER) {              // prefetch next K-tile across MFMA+barrier
            int k0 = (it + 1) * 64;
            #pragma unroll
            for (int t = 0; t < 4; ++t) {
                pa[t] = *(const float4*)(arow[t] + k0);
                pb[t] = *(const float4*)(wrow[t] + k0);
            }
        }
        #pragma unroll
        for (int kk = 0; kk < 64; kk += 32) {
            bf16x8 av[2], bv[4];
            #pragma unroll
            for (int i = 0; i < 2; ++i)
                av[i] = *(const bf16x8*)(As + (wm * 32 + i * 16 + l16) * 72 + kk + quad * 8);
            #pragma unroll
            for (int j = 0; j < 4; ++j)
                bv[j] = *(const bf16x8*)(Bs + (wn * 64 + j * 16 + l16) * 72 + kk + quad * 8);
            #pragma unroll
            for (int i = 0; i < 2; ++i)
                #pragma unroll
                for (int j = 0; j < 4; ++j)
                    acc[i][j] = __builtin_amdgcn_mfma_f32_16x16x32_bf16(av[i], bv[j], acc[i][j], 0, 0, 0);
        }
        __syncthreads();
    }

    #pragma unroll
    for (int i = 0; i < 2; ++i) {
        #pragma unroll
        for (int rr = 0; rr < 4; ++rr) {
            int gm = mbase + wm * 32 + i * 16 + quad * 4 + rr;
            float* outr = Cout + (size_t)gm * D_DIM;
            #pragma unroll
            for (int j = 0; j < 4; ++j) {
                int gn = bn * 128 + wn * 64 + j * 16 + l16;
                float bias = (gn < H_DIM) ? B0[gn] : B1[gn - H_DIM];
                outr[gn] = acc[i][j][rr] + bias;
            }
        }
    }
}

// ---------------- down-GEMM: 128x128 tile, 512 thr, K=512, bf16 A ----------------
// BLEND=false (G2): A=sh dense, W=sw3, out[gm] = acc + sb3
// BLEND=true  (E2): A=z bucket, W=ew3[e], out[row] = out[row]*shw + (acc+eb3)*expw
template<bool BLEND>
__global__ __launch_bounds__(512, 4)
void gemm_down_kernel(const u16* __restrict__ A,
                      const float* __restrict__ W, const float* __restrict__ bb,
                      float* __restrict__ C,
                      const int* __restrict__ base, const int* __restrict__ cnt,
                      const int* __restrict__ perm, const int* __restrict__ rowidx,
                      const float* __restrict__ shw, const float* __restrict__ expw)
{
    constexpr int NITER = 512 / 64;
    const int tid = threadIdx.x;
    const int bn  = blockIdx.x;            // 0..7 (128-col tiles of 1024)
    const int bm  = blockIdx.y;
    const int mbase = bm * 128;

    int pend = 0;
    if (BLEND) {
        const int tot = base[E_NUM];
        if (mbase >= tot) return;
        int e = 0;
        while (!(mbase >= base[e] && mbase < base[e + 1])) ++e;
        pend = base[e] + cnt[e];
        if (mbase >= pend) return;
        W  += (size_t)e * D_DIM * H_DIM;
        bb += e * D_DIM;
    }

    // A staging: bf16, 8 lanes cover one row's contiguous 128B k-slice; 2 rounds
    const int ar = tid >> 3;               // 0..63 row-in-round
    const int ac = tid & 7;                // 16B chunk
    const u16* arow[2];
    #pragma unroll
    for (int t = 0; t < 2; ++t)
        arow[t] = A + (size_t)(mbase + t * 64 + ar) * H_DIM + ac * 8;

    // W staging: fp32, 16 lanes cover one row's contiguous 256B k-slice; 4 rounds
    const int sr = tid >> 4;               // 0..31
    const int sc = tid & 15;
    const float* wrow[4];
    #pragma unroll
    for (int t = 0; t < 4; ++t) {
        int n = bn * 128 + t * 32 + sr;
        wrow[t] = W + (size_t)n * H_DIM + sc * 4;
    }

    __shared__ u16 As[128 * 72];
    __shared__ u16 Bs[128 * 72];

    const int lane = tid & 63;
    const int wid  = tid >> 6;
    const int wm   = wid & 3;
    const int wn   = wid >> 2;
    const int l16  = lane & 15, quad = lane >> 4;

    f32x4 acc[2][4];
    #pragma unroll
    for (int i = 0; i < 2; ++i)
        #pragma unroll
        for (int j = 0; j < 4; ++j)
            acc[i][j] = (f32x4){0.f, 0.f, 0.f, 0.f};

    uint4 pa[2]; float4 pb[4];
    #pragma unroll
    for (int t = 0; t < 2; ++t) pa[t] = *(const uint4*)(arow[t]);
    #pragma unroll
    for (int t = 0; t < 4; ++t) pb[t] = *(const float4*)(wrow[t]);

    for (int it = 0; it < NITER; ++it) {
        #pragma unroll
        for (int t = 0; t < 2; ++t)
            *(uint4*)(As + (t * 64 + ar) * 72 + ac * 8) = pa[t];
        #pragma unroll
        for (int t = 0; t < 4; ++t) {
            uint2 bv = { pack2r(pb[t].x, pb[t].y), pack2r(pb[t].z, pb[t].w) };
            *(uint2*)(Bs + (t * 32 + sr) * 72 + sc * 4) = bv;
        }
        __syncthreads();
        if (it + 1 < NITER) {
            int k0 = (it + 1) * 64;
            #pragma unroll
            for (int t = 0; t < 2; ++t) pa[t] = *(const uint4*)(arow[t] + k0);
            #pragma unroll
            for (int t = 0; t < 4; ++t) pb[t] = *(const float4*)(wrow[t] + k0);
        }
        #pragma unroll
        for (int kk = 0; kk < 64; kk += 32) {
            bf16x8 av[2], bv[4];
            #pragma unroll
            for (int i = 0; i < 2; ++i)
                av[i] = *(const bf16x8*)(As + (wm * 32 + i * 16 + l16) * 72 + kk + quad * 8);
            #pragma unroll
            for (int j = 0; j < 4; ++j)
                bv[j] = *(const bf16x8*)(Bs + (wn * 64 + j * 16 + l16) * 72 + kk + quad * 8);
            #pragma unroll
            for (int i = 0; i < 2; ++i)
                #pragma unroll
                for (int j = 0; j < 4; ++j)
                    acc[i][j] = __builtin_amdgcn_mfma_f32_16x16x32_bf16(av[i], bv[j], acc[i][j], 0, 0, 0);
        }
        __syncthreads();
    }

    if (BLEND) {
        #pragma unroll
        for (int i = 0; i < 2; ++i) {
            #pragma unroll
            for (int rr = 0; rr < 4; ++rr) {
                int p = mbase + wm * 32 + i * 16 + quad * 4 + rr;
                if (p < pend) {
                    int tok = perm[p];
                    int row = rowidx[tok];
                    float sw = shw[tok], ew = expw[tok];
                    float* outr = C + (size_t)row * D_DIM;
                    #pragma unroll
                    for (int j = 0; j < 4; ++j) {
                        int gn = bn * 128 + wn * 64 + j * 16 + l16;
                        outr[gn] = outr[gn] * sw + (acc[i][j][rr] + bb[gn]) * ew;
                    }
                }
            }
        }
    } else {
        #pragma unroll
        for (int i = 0; i < 2; ++i) {
            #pragma unroll
            for (int rr = 0; rr < 4; ++rr) {
                int gm = mbase + wm * 32 + i * 16 + quad * 4 + rr;
                float* outr = C + (size_t)gm * D_DIM;
                #pragma unroll
                for (int j = 0; j < 4; ++j) {
                    int gn = bn * 128 + wn * 64 + j * 16 + l16;
                    outr[gn] = acc[i][j][rr] + bb[gn];
                }
            }
        }
    }
}

extern "C" void kernel_launch(void* const* d_in, const int* in_sizes, int n_in,
                              void* d_out, int out_size, void* d_ws, size_t ws_size,
                              hipStream_t stream) {
    const float* x        = (const float*)d_in[0];
    const int*   index_b  = (const int*)d_in[1];
    const int*   index_t  = (const int*)d_in[2];
    const float* sw1      = (const float*)d_in[3];
    const float* sb1      = (const float*)d_in[4];
    const float* sw2      = (const float*)d_in[5];
    const float* sb2      = (const float*)d_in[6];
    const float* sw3      = (const float*)d_in[7];
    const float* sb3      = (const float*)d_in[8];
    const float* s_ln_g   = (const float*)d_in[9];
    const float* s_ln_b   = (const float*)d_in[10];
    const float* sg_w     = (const float*)d_in[11];
    const float* sg_b     = (const float*)d_in[12];
    const float* eg_w     = (const float*)d_in[13];
    const float* eg_b     = (const float*)d_in[14];
    const float* exp_bias = (const float*)d_in[15];
    const float* ew1      = (const float*)d_in[16];
    const float* eb1      = (const float*)d_in[17];
    const float* ew2      = (const float*)d_in[18];
    const float* eb2      = (const float*)d_in[19];
    const float* ew3      = (const float*)d_in[20];
    const float* eb3      = (const float*)d_in[21];
    const float* sel_ln_g = (const float*)d_in[22];
    const float* sel_ln_b = (const float*)d_in[23];
    float* out = (float*)d_out;
    char*  ws  = (char*)d_ws;

    // ---- ws layout ----
    float* x12  = (float*)(ws + 0);            // 4096x1024 fp32 (16 MB)
    float* h12  = (float*)(ws + 16777216);     // 3072x1024 fp32 (12 MB)
    u16*   sh   = (u16*)(ws + 29360128);       // 4096x512 bf16 (4 MB)
    u16*   z    = (u16*)(ws + 33554432);       // 3072x512 bf16 (3 MB)
    float* shw    = (float*)(ws + 36700160);
    float* expw   = shw + M_TOK;
    int*   top1   = (int*)(expw + M_TOK);
    int*   rowidx = top1 + M_TOK;
    int*   perm   = rowidx + M_TOK;
    int*   basep  = perm + MAXP;
    int*   cntp   = basep + 16;

    gating_kernel<<<dim3(M_TOK), dim3(256), 0, stream>>>(x, index_b, index_t,
        sg_w, sg_b, eg_w, eg_b, exp_bias, shw, expw, top1, rowidx);
    bucket_kernel<<<dim3(1), dim3(256), 0, stream>>>(top1, basep, cntp, perm);

    // fused G1 + E1: 8 x 56 = 448 blocks
    gemm_up_kernel<<<dim3(8, 32 + MAXP / 128), dim3(512), 0, stream>>>(
        x, sw1, sw2, sb1, sb2, ew1, ew2, eb1, eb2, x12, h12,
        basep, cntp, perm, rowidx);

    // fused LN (shared 4096 rows + expert 3072 rows)
    ln_all_kernel<<<dim3(BT_TOK + MAXP), dim3(256), 0, stream>>>(
        x12, h12, s_ln_g, s_ln_b, sel_ln_g, sel_ln_b, sh, z, basep, cntp);

    // G2: sh @ sw3^T -> d_out (all rows)
    gemm_down_kernel<false><<<dim3(8, 32), dim3(512), 0, stream>>>(
        sh, sw3, sb3, out, basep, cntp, perm, rowidx, shw, expw);

    // E2: z @ ew3[e]^T, blend-scatter into d_out
    gemm_down_kernel<true><<<dim3(8, MAXP / 128), dim3(512), 0, stream>>>(
        z, ew3, eb3, out, basep, cntp, perm, rowidx, shw, expw);
}

// Round 8
// 265.383 us; speedup vs baseline: 1.0513x; 1.0042x over previous
//
#include <hip/hip_runtime.h>
#include <cstdint>

typedef unsigned short u16;
typedef __bf16 bf16x8 __attribute__((ext_vector_type(8)));
typedef float f32x4 __attribute__((ext_vector_type(4)));

#define T_SEQ  2048
#define D_DIM  1024
#define H_DIM  512
#define E_NUM  8
#define M_TOK  2048
#define BT_TOK 4096
#define MAXP   3072   // M + per-expert 128-pad worst case

static __device__ __forceinline__ u16 f2bf(float f) {
    union { float f; uint32_t u; } v; v.f = f;
    uint32_t u = v.u;
    return (u16)((u + 0x7FFFu + ((u >> 16) & 1u)) >> 16);  // RNE
}
// round-half-up bf16 pack of two floats (2 adds + v_perm)
static __device__ __forceinline__ uint32_t pack2r(float a, float b) {
    union { float f; uint32_t u; } x, y; x.f = a; y.f = b;
    return ((x.u + 0x8000u) >> 16) | ((y.u + 0x8000u) & 0xffff0000u);
}

// ---------------- gating: fp32 dots, sigmoid, argmax, 2-way softmax ----------------
__global__ __launch_bounds__(256)
void gating_kernel(const float* __restrict__ x,
                   const int* __restrict__ ib, const int* __restrict__ itx,
                   const float* __restrict__ sgw, const float* __restrict__ sgb,
                   const float* __restrict__ egw, const float* __restrict__ egb,
                   const float* __restrict__ ebias,
                   float* __restrict__ shw, float* __restrict__ expw,
                   int* __restrict__ top1, int* __restrict__ rowidx)
{
    int m = blockIdx.x, tid = threadIdx.x;
    __shared__ float xs[D_DIM];
    __shared__ float sc[9];
    int row = ib[m] * T_SEQ + itx[m];
    if (tid == 0) rowidx[m] = row;
    const float* xr = x + (size_t)row * D_DIM;
    ((float4*)xs)[tid] = ((const float4*)xr)[tid];
    __syncthreads();
    int lane = tid & 63, w = tid >> 6;
    for (int sidx = w; sidx < 9; sidx += 4) {
        const float* wr = (sidx == 0) ? sgw : (egw + (size_t)(sidx - 1) * D_DIM);
        float acc = 0.f;
        for (int i = lane; i < D_DIM; i += 64) acc += xs[i] * wr[i];
        #pragma unroll
        for (int o = 32; o > 0; o >>= 1) acc += __shfl_xor(acc, o);
        if (lane == 0) sc[sidx] = acc;
    }
    __syncthreads();
    if (tid == 0) {
        float ss = 1.f / (1.f + expf(-(sc[0] + sgb[0])));
        float es[E_NUM];
        float best = -1e30f; int bi = 0;
        #pragma unroll
        for (int e = 0; e < E_NUM; ++e) {
            es[e] = 1.f / (1.f + expf(-(sc[1 + e] + egb[e])));
            float t = es[e] + ebias[e];
            if (t > best) { best = t; bi = e; }   // strict > == jnp.argmax first-max
        }
        float ts = es[bi];
        shw[m]  = 1.f / (1.f + expf(ts - ss));
        expw[m] = 1.f / (1.f + expf(ss - ts));
        top1[m] = bi;
    }
}

// ---------------- bucket tokens by expert, 128-aligned bases ----------------
__global__ void bucket_kernel(const int* __restrict__ top1,
                              int* __restrict__ base, int* __restrict__ cnt,
                              int* __restrict__ perm)
{
    __shared__ int lc[E_NUM], lb[E_NUM + 1], cur[E_NUM];
    int tid = threadIdx.x;
    if (tid < E_NUM) { lc[tid] = 0; cur[tid] = 0; }
    __syncthreads();
    for (int m = tid; m < M_TOK; m += 256) atomicAdd(&lc[top1[m]], 1);
    __syncthreads();
    if (tid == 0) {
        int bacc = 0;
        for (int e = 0; e < E_NUM; ++e) { lb[e] = bacc; bacc += (lc[e] + 127) & ~127; }
        lb[E_NUM] = bacc;
    }
    __syncthreads();
    for (int m = tid; m < M_TOK; m += 256) {
        int e = top1[m];
        int pos = lb[e] + atomicAdd(&cur[e], 1);
        perm[pos] = m;
    }
    if (tid <= E_NUM) base[tid] = lb[tid];
    if (tid < E_NUM)  cnt[tid]  = lc[tid];
}

// ---------------- fused silu-gate + LayerNorm (shared rows + expert rows) ----------------
__global__ __launch_bounds__(256)
void ln_all_kernel(const float* __restrict__ x12, const float* __restrict__ h12,
                   const float* __restrict__ gs, const float* __restrict__ bs,
                   const float* __restrict__ ge, const float* __restrict__ be,
                   u16* __restrict__ sh, u16* __restrict__ z,
                   const int* __restrict__ base, const int* __restrict__ cnt)
{
    int m = blockIdx.x;
    int tid = threadIdx.x;
    const float* X; const float* g; const float* b; u16* out; int row;
    if (m < BT_TOK) {
        X = x12; g = gs; b = bs; out = sh; row = m;
    } else {
        row = m - BT_TOK;
        int tot = base[E_NUM];
        bool valid = false;
        if (row < tot) {
            int e = 0;
            while (!(row >= base[e] && row < base[e + 1])) ++e;
            valid = (row - base[e]) < cnt[e];
        }
        if (!valid) {  // zero padding rows so E2's A-tiles are clean
            z[(size_t)row * H_DIM + tid] = 0;
            z[(size_t)row * H_DIM + tid + 256] = 0;
            return;
        }
        X = h12; g = ge; b = be; out = z;
    }
    const float* rp = X + (size_t)row * D_DIM;   // [0:512]=x1, [512:1024]=x2
    float a0 = rp[tid],       c0 = rp[H_DIM + tid];
    float a1 = rp[tid + 256], c1 = rp[H_DIM + tid + 256];
    float v0 = (a0 / (1.f + expf(-a0))) * c0;
    float v1 = (a1 / (1.f + expf(-a1))) * c1;
    float s = v0 + v1, s2 = v0 * v0 + v1 * v1;
    #pragma unroll
    for (int o = 32; o > 0; o >>= 1) {
        s  += __shfl_xor(s, o);
        s2 += __shfl_xor(s2, o);
    }
    __shared__ float red[8];
    int w = tid >> 6;
    if ((tid & 63) == 0) { red[w] = s; red[4 + w] = s2; }
    __syncthreads();
    s  = red[0] + red[1] + red[2] + red[3];
    s2 = red[4] + red[5] + red[6] + red[7];
    float mu  = s * (1.f / H_DIM);
    float var = s2 * (1.f / H_DIM) - mu * mu;
    float inv = rsqrtf(var + 1e-5f);
    out[(size_t)row * H_DIM + tid]       = f2bf((v0 - mu) * inv * g[tid] + b[tid]);
    out[(size_t)row * H_DIM + tid + 256] = f2bf((v1 - mu) * inv * g[tid + 256] + b[tid + 256]);
}

// XCD-aware decode: blocks are (assumed) round-robined over 8 XCDs by id%8.
// All 8 bn-tiles of one row-group g land on ONE XCD: id = g%8 + 8*bn + 64*(g/8).
// decode: bn=(id>>3)&7, g=(id&7)+8*(id>>6). Bijective for grids of 8*NG blocks.
static __device__ __forceinline__ void decode_swz(int id, int& bn, int& g) {
    bn = (id >> 3) & 7;
    g  = (id & 7) + ((id >> 6) << 3);
}

// ---------------- fused up-GEMM (G1 + E1): 128x128 tile, 512 thr, K=1024 ----------------
// g < 32  : G1  rows m=g*128..,   A=x dense,    W=sw1|sw2, out=x12 (+sb1|sb2)
// g >= 32 : E1  bucket tile g-32, A=x gathered, W=ew1|ew2[e], out=h12 (+eb1|eb2[e])
// Safe to fuse: both halves write disjoint buffers, read only x/weights.
__global__ __launch_bounds__(512, 4)
void gemm_up_kernel(const float* __restrict__ x,
                    const float* __restrict__ sw1, const float* __restrict__ sw2,
                    const float* __restrict__ sb1, const float* __restrict__ sb2,
                    const float* __restrict__ ew1, const float* __restrict__ ew2,
                    const float* __restrict__ eb1, const float* __restrict__ eb2,
                    float* __restrict__ x12, float* __restrict__ h12,
                    const int* __restrict__ base, const int* __restrict__ cnt,
                    const int* __restrict__ perm, const int* __restrict__ rowidx)
{
    constexpr int NITER = 1024 / 64;
    const int tid = threadIdx.x;
    int bn, g;
    decode_swz(blockIdx.x, bn, g);         // 448 blocks: g in [0,56)

    const int sr = tid >> 4;               // 0..31 row-in-round
    const int sc = tid & 15;               // 16B chunk (float4) within 256B k-slice

    const float *W0, *W1, *B0, *B1;
    float* Cout;
    int mbase;
    const float* arow[4];                  // K-invariant A row pointers (4 rounds)

    if (g < 32) {                          // ---- G1 ----
        mbase = g * 128;
        W0 = sw1; W1 = sw2; B0 = sb1; B1 = sb2;
        Cout = x12;
        #pragma unroll
        for (int t = 0; t < 4; ++t)
            arow[t] = x + (size_t)(mbase + t * 32 + sr) * D_DIM + sc * 4;
    } else {                               // ---- E1 ----
        mbase = (g - 32) * 128;
        const int tot = base[E_NUM];
        if (mbase >= tot) return;          // block-uniform exit before any barrier
        int e = 0;
        while (!(mbase >= base[e] && mbase < base[e + 1])) ++e;
        const int pend = base[e] + cnt[e];
        if (mbase >= pend) return;
        W0 = ew1 + (size_t)e * H_DIM * D_DIM;
        W1 = ew2 + (size_t)e * H_DIM * D_DIM;
        B0 = eb1 + e * H_DIM;
        B1 = eb2 + e * H_DIM;
        Cout = h12;
        #pragma unroll
        for (int t = 0; t < 4; ++t) {
            int p  = mbase + t * 32 + sr;
            int pp = (p < pend) ? p : (pend - 1);   // clamp pad rows
            arow[t] = x + (size_t)rowidx[perm[pp]] * D_DIM + sc * 4;
        }
    }
    const float* wrow[4];
    #pragma unroll
    for (int t = 0; t < 4; ++t) {
        int n = bn * 128 + t * 32 + sr;
        wrow[t] = ((n < H_DIM) ? (W0 + (size_t)n * D_DIM)
                               : (W1 + (size_t)(n - H_DIM) * D_DIM)) + sc * 4;
    }

    __shared__ u16 As[128 * 72];
    __shared__ u16 Bs[128 * 72];

    const int lane = tid & 63;
    const int wid  = tid >> 6;             // 0..7
    const int wm   = wid & 3;              // 32-row band
    const int wn   = wid >> 2;             // 64-col band
    const int l16  = lane & 15, quad = lane >> 4;

    f32x4 acc[2][4];
    #pragma unroll
    for (int i = 0; i < 2; ++i)
        #pragma unroll
        for (int j = 0; j < 4; ++j)
            acc[i][j] = (f32x4){0.f, 0.f, 0.f, 0.f};

    float4 pa[4], pb[4];
    #pragma unroll
    for (int t = 0; t < 4; ++t) { pa[t] = *(const float4*)(arow[t]); pb[t] = *(const float4*)(wrow[t]); }

    for (int it = 0; it < NITER; ++it) {
        #pragma unroll
        for (int t = 0; t < 4; ++t) {      // cvt + coalesced 8B LDS stores
            int r = t * 32 + sr;
            uint2 av = { pack2r(pa[t].x, pa[t].y), pack2r(pa[t].z, pa[t].w) };
            uint2 bv = { pack2r(pb[t].x, pb[t].y), pack2r(pb[t].z, pb[t].w) };
            *(uint2*)(As + r * 72 + sc * 4) = av;
            *(uint2*)(Bs + r * 72 + sc * 4) = bv;
        }
        __syncthreads();
        if (it + 1 < NITER) {              // prefetch next K-tile across MFMA+barrier
            int k0 = (it + 1) * 64;
            #pragma unroll
            for (int t = 0; t < 4; ++t) {
                pa[t] = *(const float4*)(arow[t] + k0);
                pb[t] = *(const float4*)(wrow[t] + k0);
            }
        }
        #pragma unroll
        for (int kk = 0; kk < 64; kk += 32) {
            bf16x8 av[2], bv[4];
            #pragma unroll
            for (int i = 0; i < 2; ++i)
                av[i] = *(const bf16x8*)(As + (wm * 32 + i * 16 + l16) * 72 + kk + quad * 8);
            #pragma unroll
            for (int j = 0; j < 4; ++j)
                bv[j] = *(const bf16x8*)(Bs + (wn * 64 + j * 16 + l16) * 72 + kk + quad * 8);
            #pragma unroll
            for (int i = 0; i < 2; ++i)
                #pragma unroll
                for (int j = 0; j < 4; ++j)
                    acc[i][j] = __builtin_amdgcn_mfma_f32_16x16x32_bf16(av[i], bv[j], acc[i][j], 0, 0, 0);
        }
        __syncthreads();
    }

    #pragma unroll
    for (int i = 0; i < 2; ++i) {
        #pragma unroll
        for (int rr = 0; rr < 4; ++rr) {
            int gm = mbase + wm * 32 + i * 16 + quad * 4 + rr;
            float* outr = Cout + (size_t)gm * D_DIM;
            #pragma unroll
            for (int j = 0; j < 4; ++j) {
                int gn = bn * 128 + wn * 64 + j * 16 + l16;
                float bias = (gn < H_DIM) ? B0[gn] : B1[gn - H_DIM];
                outr[gn] = acc[i][j][rr] + bias;
            }
        }
    }
}

// ---------------- down-GEMM: 128x128 tile, 512 thr, K=512 ----------------
// BLEND=false (G2): A=sh dense rows, W=sw3, out[gm] = acc + sb3 (whole d_out)
// BLEND=true  (E2): A=z bucket tile, W=ew3[e], out[row] = out[row]*shw + (acc+eb3)*expw
// MUST be two separate dispatches: E2 reads what G2 wrote (no intra-launch ordering).
template<bool BLEND>
__global__ __launch_bounds__(512, 4)
void gemm_down_kernel(const u16* __restrict__ A,
                      const float* __restrict__ W, const float* __restrict__ bb,
                      float* __restrict__ C,
                      const int* __restrict__ base, const int* __restrict__ cnt,
                      const int* __restrict__ perm, const int* __restrict__ rowidx,
                      const float* __restrict__ shw, const float* __restrict__ expw)
{
    constexpr int NITER = 512 / 64;
    const int tid = threadIdx.x;
    int bn, g;
    decode_swz(blockIdx.x, bn, g);         // G2: 256 blocks g<32; E2: 192 blocks g<24

    int mbase = g * 128, pend = 0;
    if (BLEND) {
        const int tot = base[E_NUM];
        if (mbase >= tot) return;
        int e = 0;
        while (!(mbase >= base[e] && mbase < base[e + 1])) ++e;
        pend = base[e] + cnt[e];
        if (mbase >= pend) return;
        W  += (size_t)e * D_DIM * H_DIM;
        bb += e * D_DIM;
    }

    // A staging: bf16, 8 lanes cover one row's contiguous 128B k-slice; 2 rounds
    const int ar = tid >> 3;               // 0..63 row-in-round
    const int ac = tid & 7;                // 16B chunk
    const u16* arow[2];
    #pragma unroll
    for (int t = 0; t < 2; ++t)
        arow[t] = A + (size_t)(mbase + t * 64 + ar) * H_DIM + ac * 8;

    // W staging: fp32, 16 lanes cover one row's contiguous 256B k-slice; 4 rounds
    const int sr = tid >> 4;               // 0..31
    const int sc = tid & 15;
    const float* wrow[4];
    #pragma unroll
    for (int t = 0; t < 4; ++t) {
        int n = bn * 128 + t * 32 + sr;
        wrow[t] = W + (size_t)n * H_DIM + sc * 4;
    }

    __shared__ u16 As[128 * 72];
    __shared__ u16 Bs[128 * 72];

    const int lane = tid & 63;
    const int wid  = tid >> 6;
    const int wm   = wid & 3;
    const int wn   = wid >> 2;
    const int l16  = lane & 15, quad = lane >> 4;

    f32x4 acc[2][4];
    #pragma unroll
    for (int i = 0; i < 2; ++i)
        #pragma unroll
        for (int j = 0; j < 4; ++j)
            acc[i][j] = (f32x4){0.f, 0.f, 0.f, 0.f};

    uint4 pa[2]; float4 pb[4];
    #pragma unroll
    for (int t = 0; t < 2; ++t) pa[t] = *(const uint4*)(arow[t]);
    #pragma unroll
    for (int t = 0; t < 4; ++t) pb[t] = *(const float4*)(wrow[t]);

    for (int it = 0; it < NITER; ++it) {
        #pragma unroll
        for (int t = 0; t < 2; ++t)
            *(uint4*)(As + (t * 64 + ar) * 72 + ac * 8) = pa[t];
        #pragma unroll
        for (int t = 0; t < 4; ++t) {
            uint2 bv = { pack2r(pb[t].x, pb[t].y), pack2r(pb[t].z, pb[t].w) };
            *(uint2*)(Bs + (t * 32 + sr) * 72 + sc * 4) = bv;
        }
        __syncthreads();
        if (it + 1 < NITER) {
            int k0 = (it + 1) * 64;
            #pragma unroll
            for (int t = 0; t < 2; ++t) pa[t] = *(const uint4*)(arow[t] + k0);
            #pragma unroll
            for (int t = 0; t < 4; ++t) pb[t] = *(const float4*)(wrow[t] + k0);
        }
        #pragma unroll
        for (int kk = 0; kk < 64; kk += 32) {
            bf16x8 av[2], bv[4];
            #pragma unroll
            for (int i = 0; i < 2; ++i)
                av[i] = *(const bf16x8*)(As + (wm * 32 + i * 16 + l16) * 72 + kk + quad * 8);
            #pragma unroll
            for (int j = 0; j < 4; ++j)
                bv[j] = *(const bf16x8*)(Bs + (wn * 64 + j * 16 + l16) * 72 + kk + quad * 8);
            #pragma unroll
            for (int i = 0; i < 2; ++i)
                #pragma unroll
                for (int j = 0; j < 4; ++j)
                    acc[i][j] = __builtin_amdgcn_mfma_f32_16x16x32_bf16(av[i], bv[j], acc[i][j], 0, 0, 0);
        }
        __syncthreads();
    }

    if (BLEND) {
        #pragma unroll
        for (int i = 0; i < 2; ++i) {
            #pragma unroll
            for (int rr = 0; rr < 4; ++rr) {
                int p = mbase + wm * 32 + i * 16 + quad * 4 + rr;
                if (p < pend) {
                    int tok = perm[p];
                    int row = rowidx[tok];
                    float sw = shw[tok], ew = expw[tok];
                    float* outr = C + (size_t)row * D_DIM;
                    #pragma unroll
                    for (int j = 0; j < 4; ++j) {
                        int gn = bn * 128 + wn * 64 + j * 16 + l16;
                        outr[gn] = outr[gn] * sw + (acc[i][j][rr] + bb[gn]) * ew;
                    }
                }
            }
        }
    } else {
        #pragma unroll
        for (int i = 0; i < 2; ++i) {
            #pragma unroll
            for (int rr = 0; rr < 4; ++rr) {
                int gm = mbase + wm * 32 + i * 16 + quad * 4 + rr;
                float* outr = C + (size_t)gm * D_DIM;
                #pragma unroll
                for (int j = 0; j < 4; ++j) {
                    int gn = bn * 128 + wn * 64 + j * 16 + l16;
                    outr[gn] = acc[i][j][rr] + bb[gn];
                }
            }
        }
    }
}

extern "C" void kernel_launch(void* const* d_in, const int* in_sizes, int n_in,
                              void* d_out, int out_size, void* d_ws, size_t ws_size,
                              hipStream_t stream) {
    const float* x        = (const float*)d_in[0];
    const int*   index_b  = (const int*)d_in[1];
    const int*   index_t  = (const int*)d_in[2];
    const float* sw1      = (const float*)d_in[3];
    const float* sb1      = (const float*)d_in[4];
    const float* sw2      = (const float*)d_in[5];
    const float* sb2      = (const float*)d_in[6];
    const float* sw3      = (const float*)d_in[7];
    const float* sb3      = (const float*)d_in[8];
    const float* s_ln_g   = (const float*)d_in[9];
    const float* s_ln_b   = (const float*)d_in[10];
    const float* sg_w     = (const float*)d_in[11];
    const float* sg_b     = (const float*)d_in[12];
    const float* eg_w     = (const float*)d_in[13];
    const float* eg_b     = (const float*)d_in[14];
    const float* exp_bias = (const float*)d_in[15];
    const float* ew1      = (const float*)d_in[16];
    const float* eb1      = (const float*)d_in[17];
    const float* ew2      = (const float*)d_in[18];
    const float* eb2      = (const float*)d_in[19];
    const float* ew3      = (const float*)d_in[20];
    const float* eb3      = (const float*)d_in[21];
    const float* sel_ln_g = (const float*)d_in[22];
    const float* sel_ln_b = (const float*)d_in[23];
    float* out = (float*)d_out;
    char*  ws  = (char*)d_ws;

    // ---- ws layout ----
    float* x12  = (float*)(ws + 0);            // 4096x1024 fp32 (16 MB)
    float* h12  = (float*)(ws + 16777216);     // 3072x1024 fp32 (12 MB)
    u16*   sh   = (u16*)(ws + 29360128);       // 4096x512 bf16 (4 MB)
    u16*   z    = (u16*)(ws + 33554432);       // 3072x512 bf16 (3 MB)
    float* shw    = (float*)(ws + 36700160);
    float* expw   = shw + M_TOK;
    int*   top1   = (int*)(expw + M_TOK);
    int*   rowidx = top1 + M_TOK;
    int*   perm   = rowidx + M_TOK;
    int*   basep  = perm + MAXP;
    int*   cntp   = basep + 16;

    gating_kernel<<<dim3(M_TOK), dim3(256), 0, stream>>>(x, index_b, index_t,
        sg_w, sg_b, eg_w, eg_b, exp_bias, shw, expw, top1, rowidx);
    bucket_kernel<<<dim3(1), dim3(256), 0, stream>>>(top1, basep, cntp, perm);

    // fused G1 + E1: 448 blocks, XCD-swizzled 1-D grid (disjoint outputs -> safe)
    gemm_up_kernel<<<dim3(448), dim3(512), 0, stream>>>(
        x, sw1, sw2, sb1, sb2, ew1, ew2, eb1, eb2, x12, h12,
        basep, cntp, perm, rowidx);

    // fused LN (shared 4096 rows + expert 3072 rows)
    ln_all_kernel<<<dim3(BT_TOK + MAXP), dim3(256), 0, stream>>>(
        x12, h12, s_ln_g, s_ln_b, sel_ln_g, sel_ln_b, sh, z, basep, cntp);

    // G2: sh @ sw3^T -> d_out (all rows). 256 blocks, swizzled.
    gemm_down_kernel<false><<<dim3(256), dim3(512), 0, stream>>>(
        sh, sw3, sb3, out, basep, cntp, perm, rowidx, shw, expw);

    // E2: z @ ew3[e]^T, blend-scatter into d_out. 192 blocks, swizzled.
    // Separate dispatch AFTER G2 (reads d_out rows G2 wrote).
    gemm_down_kernel<true><<<dim3(192), dim3(512), 0, stream>>>(
        z, ew3, eb3, out, basep, cntp, perm, rowidx, shw, expw);
}